// Round 12
// baseline (411.686 us; speedup 1.0000x reference)
//
#include <hip/hip_runtime.h>

#define B_ 64
#define T_ 256
#define E_ 256
#define H_ 256
#define G4 1024   // 4*H
#define L_ 9

typedef __attribute__((ext_vector_type(8))) short bf16x8;
typedef __attribute__((ext_vector_type(4))) float f32x4;
typedef __attribute__((ext_vector_type(4))) unsigned uint4v;
typedef _Float16 half2v __attribute__((ext_vector_type(2)));

__device__ __forceinline__ ushort f2bf(float x){
  unsigned u = __float_as_uint(x);
  unsigned r = (u + 0x7FFFu + ((u >> 16) & 1u)) >> 16;
  return (ushort)r;
}
__device__ __forceinline__ float bf2f(unsigned u16v){
  return __uint_as_float(u16v << 16);
}
__device__ __forceinline__ float fsig(float x){
  return __builtin_amdgcn_rcpf(1.f + __expf(-x));
}
__device__ __forceinline__ float ftanh(float x){
  return 1.f - 2.f * __builtin_amdgcn_rcpf(__expf(2.f * x) + 1.f);
}
__device__ __forceinline__ int sdot4(unsigned a, unsigned b, int c){
#if __has_builtin(__builtin_amdgcn_sdot4)
  return __builtin_amdgcn_sdot4((int)a, (int)b, c, false);
#else
  int r = c;
  #pragma unroll
  for (int j = 0; j < 4; j++){
    int av = (int)(signed char)((a >> (8 * j)) & 0xFF);
    int bv = (int)(signed char)((b >> (8 * j)) & 0xFF);
    r += av * bv;
  }
  return r;
#endif
}

// ===== fused prep: WT | Uq(i8 quant, pair-layout) | gather | seqlen =====
__global__ void k_prep(const int* __restrict__ inp, const float* __restrict__ emb,
                       const float* __restrict__ Wf, const float* __restrict__ Wb,
                       const float* __restrict__ Uf, const float* __restrict__ Ub,
                       ushort* __restrict__ WT, unsigned* __restrict__ Uq,
                       float* __restrict__ su, ushort* __restrict__ X,
                       int* __restrict__ lens, float* __restrict__ out_len){
  int bid = blockIdx.x, tid = threadIdx.x;
  if (bid < 2048){                                   // W -> bf16 transposed [dir][n][k]
    int idx = bid * 256 + tid;
    int dir = idx >> 18; int rem = idx & 262143;
    int n = rem >> 8, k = rem & 255;
    const float* W = dir ? Wb : Wf;
    WT[idx] = f2bf(W[k * G4 + n]);
  } else if (bid < 4096){                            // U col -> i8 [dir][u][khalf][g][kk<32]
    int idx = bid - 2048;                            // dir*1024 + c
    int dir = idx >> 10, cc = idx & 1023;
    int u = cc & 255, g = cc >> 8;
    const float* U = dir ? Ub : Uf;
    float v = U[tid * G4 + cc];                      // tid = k
    __shared__ float red[4];
    __shared__ float ssu;
    __shared__ char qb[256];
    float a = fabsf(v);
    #pragma unroll
    for (int off = 32; off; off >>= 1) a = fmaxf(a, __shfl_xor(a, off));
    int lane = tid & 63, w = tid >> 6;
    if (lane == 0) red[w] = a;
    __syncthreads();
    if (tid == 0){
      float m = fmaxf(fmaxf(red[0], red[1]), fmaxf(red[2], red[3]));
      float s = fmaxf(m, 1e-20f) * (1.f / 127.f);
      ssu = s;
      su[idx] = s;
    }
    __syncthreads();
    float s = ssu;
    int q = __float2int_rn(v / s);
    q = max(-127, min(127, q));
    qb[tid] = (char)q;
    __syncthreads();
    if (tid < 64){                                   // word w covers k=4w..4w+3
      int khalf = tid >> 5, kk = tid & 31;
      Uq[dir * 65536 + u * 256 + khalf * 128 + g * 32 + kk] =
          *(const unsigned*)&qb[tid * 4];
    }
  } else if (bid < 6144){                            // X = bf16(emb[inp])
    int idx = (bid - 4096) * 256 + tid;
    int m = idx >> 5, koff = (idx & 31) * 8;
    int tok = inp[m];
    const float* src = emb + (size_t)tok * E_ + koff;
    float4 a = *(const float4*)src;
    float4 b = *(const float4*)(src + 4);
    uint4 o;
    o.x = (unsigned)f2bf(a.x) | ((unsigned)f2bf(a.y) << 16);
    o.y = (unsigned)f2bf(a.z) | ((unsigned)f2bf(a.w) << 16);
    o.z = (unsigned)f2bf(b.x) | ((unsigned)f2bf(b.y) << 16);
    o.w = (unsigned)f2bf(b.z) | ((unsigned)f2bf(b.w) << 16);
    *(uint4*)(X + m * E_ + koff) = o;
  } else {                                           // seq_lens: 16 blocks x 4 waves
    int w = tid >> 6, lane = tid & 63;
    int b = (bid - 6144) * 4 + w;
    int c = 0;
    for (int t = lane; t < T_; t += 64) c += (inp[b * T_ + t] != 0);
    for (int off = 32; off; off >>= 1) c += __shfl_xor(c, off);
    if (lane == 0){ lens[b] = c; out_len[b] = (float)c; }
  }
}

// ===== Z = X @ W + bias (bf16 MFMA) -> packed bf16 [tok][j<256][gate<4] =====
__global__ __launch_bounds__(256) void k_gemm(const ushort* __restrict__ X,
        const ushort* __restrict__ WT, const float* __restrict__ bf_,
        const float* __restrict__ bb_, ushort* __restrict__ Zpf, ushort* __restrict__ Zpb){
  int zi = blockIdx.z;
  const ushort* wt = WT + zi * 262144;
  const float* bias = zi ? bb_ : bf_;
  ushort* Zp = zi ? Zpb : Zpf;
  int m0 = blockIdx.x * 128, n0 = blockIdx.y * 128;
  __shared__ ushort As[128][40];
  __shared__ ushort Bs[128][40];
  int tid = threadIdx.x;
  int sr = tid >> 1, sk = (tid & 1) * 16;
  const ushort* xg = X + (m0 + sr) * E_ + sk;
  const ushort* wg = wt + (n0 + sr) * E_ + sk;
  f32x4 acc[4][4] = {};
  int lane = tid & 63, wv = tid >> 6;
  int wr = wv >> 1, wc = wv & 1;
  int lrow = lane & 15, kf = (lane >> 4) * 8;
  for (int k0 = 0; k0 < E_; k0 += 32){
    uint4 a0 = *(const uint4*)(xg + k0);
    uint4 a1 = *(const uint4*)(xg + k0 + 8);
    uint4 b0 = *(const uint4*)(wg + k0);
    uint4 b1 = *(const uint4*)(wg + k0 + 8);
    *(uint4*)&As[sr][sk]     = a0;  *(uint4*)&As[sr][sk + 8] = a1;
    *(uint4*)&Bs[sr][sk]     = b0;  *(uint4*)&Bs[sr][sk + 8] = b1;
    __syncthreads();
    bf16x8 af[4], bfr[4];
    #pragma unroll
    for (int i = 0; i < 4; i++) af[i]  = *(const bf16x8*)&As[wr * 64 + i * 16 + lrow][kf];
    #pragma unroll
    for (int i = 0; i < 4; i++) bfr[i] = *(const bf16x8*)&Bs[wc * 64 + i * 16 + lrow][kf];
    #pragma unroll
    for (int i = 0; i < 4; i++)
      #pragma unroll
      for (int j = 0; j < 4; j++)
        acc[i][j] = __builtin_amdgcn_mfma_f32_16x16x32_bf16(af[i], bfr[j], acc[i][j], 0, 0, 0);
    __syncthreads();
  }
  int crow = (lane >> 4) * 4;
  #pragma unroll
  for (int j = 0; j < 4; j++){
    int col = n0 + wc * 64 + j * 16 + lrow;
    float bv = bias[col];
    int gg = col >> 8, jj = col & 255;
    #pragma unroll
    for (int i = 0; i < 4; i++){
      int rbase = m0 + wr * 64 + i * 16 + crow;
      #pragma unroll
      for (int r = 0; r < 4; r++)
        Zp[((size_t)(rbase + r) * 256 + jj) * 4 + gg] = f2bf(acc[i][j][r] + bv);
    }
  }
}

// ===== LSTM recurrence v12: R10 pair layout, 8-step chunks, NO globals between
// per-step barriers. Z staged global->regs->LDS per chunk; H buffered in LDS and
// flushed per chunk (one chunk late, so stores retire before their drain).
__global__ __launch_bounds__(512, 2) void k_recur12(
    const ushort* __restrict__ Zpf, const ushort* __restrict__ Zpb,
    const unsigned* __restrict__ Uq, const float* __restrict__ su,
    const int* __restrict__ lens, ushort* __restrict__ hf16, ushort* __restrict__ hb16){
  int bid = blockIdx.x;
  int dir = bid >> 6, b = bid & 63;
  const uint2* Zp = (const uint2*)(dir ? Zpb : Zpf);
  unsigned* Hw = (unsigned*)(dir ? hb16 : hf16);     // u32 view of bf16 H
  int tid = threadIdx.x;
  int u = tid >> 1, khalf = tid & 1;
  float sc0 = su[dir * 1024 +        u] * (1.f / 127.f);
  float sc1 = su[dir * 1024 + 256 +  u] * (1.f / 127.f);
  float sc2 = su[dir * 1024 + 512 +  u] * (1.f / 127.f);
  float sc3 = su[dir * 1024 + 768 +  u] * (1.f / 127.f);
  int alen = lens[b];

  // 4 gates x 8 chunks of U (i8) in registers, asm-defined (no rematerialization)
  uint4v uq[4][8];
  {
    const unsigned* p = Uq + dir * 65536 + u * 256 + khalf * 128;
    #pragma unroll
    for (int g = 0; g < 4; g++)
      #pragma unroll
      for (int i = 0; i < 8; i++)
        asm volatile("global_load_dwordx4 %0, %1, off"
                     : "=v"(uq[g][i]) : "v"(p + g * 32 + i * 4));
    asm volatile("s_waitcnt vmcnt(0)" ::: "memory");
    __builtin_amdgcn_sched_barrier(0);
  }

  __shared__ unsigned hq[2][64];        // i8 h, word w = h[4w..4w+3]
  __shared__ uint2    zbuf[2][8][256];  // staged Z, 32 KB
  __shared__ ushort   hbufL[2][8][256]; // buffered bf16 h, 8 KB

  // prologue: stage chunk 0
  uint2 zstage[4];
  #pragma unroll
  for (int j = 0; j < 4; j++){
    int e = j * 512 + tid, tt = e >> 8, uu = e & 255;
    int t = dir ? (255 - tt) : tt;
    zstage[j] = Zp[(size_t)(b * 256 + t) * 256 + uu];
  }
  if (tid < 128) ((unsigned*)hq)[tid] = 0u;
  #pragma unroll
  for (int j = 0; j < 4; j++){
    int e = j * 512 + tid;
    zbuf[0][e >> 8][e & 255] = zstage[j];
  }
  __syncthreads();

  float c_st = 0.f, h_st = 0.f;

  for (int c = 0; c < 32; ++c){
    int cb = c & 1;
    // issue next chunk's Z loads (retire during this chunk's 8 steps)
    if (c < 31){
      #pragma unroll
      for (int j = 0; j < 4; j++){
        int e = j * 512 + tid, tt = e >> 8, uu = e & 255;
        int s2 = (c + 1) * 8 + tt;
        int t = dir ? (255 - s2) : s2;
        zstage[j] = Zp[(size_t)(b * 256 + t) * 256 + uu];
      }
    }
    // flush PREVIOUS chunk's H (stores retire during this chunk)
    if (c > 0){
      #pragma unroll
      for (int j = 0; j < 2; j++){
        int e = j * 512 + tid, tt = e >> 7, p = e & 127;
        int s2 = (c - 1) * 8 + tt;
        int t = dir ? (255 - s2) : s2;
        unsigned wv = ((unsigned*)hbufL[cb ^ 1])[tt * 128 + p];
        Hw[(size_t)(b * 256 + t) * 128 + p] = wv;
      }
    }
    // 8 steps: no global ops inside
    #pragma unroll
    for (int tt = 0; tt < 8; ++tt){
      int s_ = c * 8 + tt;
      int t = dir ? (255 - s_) : s_;
      int cur = s_ & 1, nxt = cur ^ 1;
      uint2 zw = zbuf[cb][tt][u];
      int a0 = 0, a1 = 0, a2 = 0, a3 = 0;
      const uint4* hp = (const uint4*)&hq[cur][khalf * 32];
      #pragma unroll
      for (int i = 0; i < 8; i++){
        uint4 hv = hp[i];
        a0 = sdot4(uq[0][i][0], hv.x, a0);  a0 = sdot4(uq[0][i][1], hv.y, a0);
        a0 = sdot4(uq[0][i][2], hv.z, a0);  a0 = sdot4(uq[0][i][3], hv.w, a0);
        a1 = sdot4(uq[1][i][0], hv.x, a1);  a1 = sdot4(uq[1][i][1], hv.y, a1);
        a1 = sdot4(uq[1][i][2], hv.z, a1);  a1 = sdot4(uq[1][i][3], hv.w, a1);
        a2 = sdot4(uq[2][i][0], hv.x, a2);  a2 = sdot4(uq[2][i][1], hv.y, a2);
        a2 = sdot4(uq[2][i][2], hv.z, a2);  a2 = sdot4(uq[2][i][3], hv.w, a2);
        a3 = sdot4(uq[3][i][0], hv.x, a3);  a3 = sdot4(uq[3][i][1], hv.y, a3);
        a3 = sdot4(uq[3][i][2], hv.z, a3);  a3 = sdot4(uq[3][i][3], hv.w, a3);
      }
      a0 += __shfl_xor(a0, 1);
      a1 += __shfl_xor(a1, 1);
      a2 += __shfl_xor(a2, 1);
      a3 += __shfl_xor(a3, 1);
      float zi = bf2f(zw.x & 0xffffu) + (float)a0 * sc0;
      float zf = bf2f(zw.x >> 16)     + (float)a1 * sc1;
      float zg = bf2f(zw.y & 0xffffu) + (float)a2 * sc2;
      float zo = bf2f(zw.y >> 16)     + (float)a3 * sc3;
      if (t < alen){
        c_st = fsig(zf) * c_st + fsig(zi) * ftanh(zg);
        h_st = fsig(zo) * ftanh(c_st);
      }
      if (khalf == 0){
        int ri = __float2int_rn(h_st * 127.f);
        ((char*)hq[nxt])[u] = (char)ri;
        hbufL[cb][tt][u] = f2bf(h_st);
      }
      __syncthreads();
    }
    // write next chunk's staged Z (loads have had ~8 steps to land)
    if (c < 31){
      #pragma unroll
      for (int j = 0; j < 4; j++){
        int e = j * 512 + tid;
        zbuf[cb ^ 1][e >> 8][e & 255] = zstage[j];
      }
    }
    __syncthreads();
  }
  // epilogue: flush chunk 31's H (buffer 31&1 = 1)
  #pragma unroll
  for (int j = 0; j < 2; j++){
    int e = j * 512 + tid, tt = e >> 7, p = e & 127;
    int s2 = 248 + tt;
    int t = dir ? (255 - s2) : s2;
    Hw[(size_t)(b * 256 + t) * 128 + p] = ((unsigned*)hbufL[1])[tt * 128 + p];
  }
}

// ===== pot = [hf|hb] @ Wd + bd (one wave per row, bf16 h) =====
__global__ __launch_bounds__(256) void k_pot(const ushort* __restrict__ hf16,
        const ushort* __restrict__ hb16, const float* __restrict__ Wd,
        const float* __restrict__ bd, float* __restrict__ out, int* __restrict__ cnt){
  if (blockIdx.x == 0 && threadIdx.x == 0) *cnt = 0;
  int lane = threadIdx.x & 63, wid = threadIdx.x >> 6;
  int m = blockIdx.x * 4 + wid;
  uint2 ua = *(const uint2*)&hf16[(size_t)m * H_ + lane * 4];
  uint2 ub = *(const uint2*)&hb16[(size_t)m * H_ + lane * 4];
  float av[4] = {bf2f(ua.x & 0xFFFFu), bf2f(ua.x >> 16), bf2f(ua.y & 0xFFFFu), bf2f(ua.y >> 16)};
  float bv[4] = {bf2f(ub.x & 0xFFFFu), bf2f(ub.x >> 16), bf2f(ub.y & 0xFFFFu), bf2f(ub.y >> 16)};
  float acc[9];
  #pragma unroll
  for (int l = 0; l < 9; l++) acc[l] = 0.f;
  #pragma unroll
  for (int i = 0; i < 4; i++){
    int r = lane * 4 + i;
    #pragma unroll
    for (int l = 0; l < 9; l++)
      acc[l] += av[i] * Wd[r * 9 + l] + bv[i] * Wd[(H_ + r) * 9 + l];
  }
  #pragma unroll
  for (int off = 32; off; off >>= 1)
    #pragma unroll
    for (int l = 0; l < 9; l++) acc[l] += __shfl_xor(acc[l], off);
  if (lane == 0){
    #pragma unroll
    for (int l = 0; l < 9; l++) out[(size_t)m * 9 + l] = acc[l] + bd[l];
  }
}

// ===== CRF log-likelihood + loss (fused, last-block reduce) =====
__global__ void k_post(const float* __restrict__ out, const int* __restrict__ tags,
                       const float* __restrict__ trans, const int* __restrict__ lens,
                       float* __restrict__ lln, int* cnt, float* __restrict__ loss_out){
  int b = blockIdx.x, lane = threadIdx.x;
  int len = lens[b];
  const float* pot = out + (size_t)b * T_ * 9;
  float up = 0.f, bp = 0.f;
  for (int t = lane; t < T_; t += 64){
    int tg = tags[b * T_ + t];
    if (t < len) up += pot[t * 9 + tg];
    if (t + 1 < len){
      int tg2 = tags[b * T_ + t + 1];
      bp += trans[tg * 9 + tg2];
    }
  }
  for (int off = 32; off; off >>= 1){ up += __shfl_xor(up, off); bp += __shfl_xor(bp, off); }
  float alpha = 0.f;
  if (lane < 9){
    float tr[9];
    #pragma unroll
    for (int i = 0; i < 9; i++) tr[i] = trans[i * 9 + lane];
    alpha = pot[lane];
    for (int t = 1; t < T_; ++t){
      float v[9];
      #pragma unroll
      for (int i = 0; i < 9; i++) v[i] = __shfl(alpha, i) + tr[i];
      float mx = v[0];
      #pragma unroll
      for (int i = 1; i < 9; i++) mx = fmaxf(mx, v[i]);
      float sum = 0.f;
      #pragma unroll
      for (int i = 0; i < 9; i++) sum += __expf(v[i] - mx);
      float an = pot[t * 9 + lane] + mx + __logf(sum);
      if (t < len) alpha = an;
    }
  }
  float mx2 = -3.4e38f;
  for (int i = 0; i < 9; i++){ float a = __shfl(alpha, i); mx2 = fmaxf(mx2, a); }
  float s2 = 0.f;
  for (int i = 0; i < 9; i++){ float a = __shfl(alpha, i); s2 += __expf(a - mx2); }
  float lse = mx2 + __logf(s2);
  __shared__ int lastf;
  if (lane == 0){
    __hip_atomic_store(&lln[b], (up + bp - lse) / (float)len,
                       __ATOMIC_RELAXED, __HIP_MEMORY_SCOPE_AGENT);
    int old = __hip_atomic_fetch_add(cnt, 1, __ATOMIC_ACQ_REL, __HIP_MEMORY_SCOPE_AGENT);
    lastf = (old == 63);
  }
  __syncthreads();
  if (lastf){
    float v = __hip_atomic_load(&lln[lane], __ATOMIC_RELAXED, __HIP_MEMORY_SCOPE_AGENT);
    for (int off = 32; off; off >>= 1) v += __shfl_xor(v, off);
    if (lane == 0) loss_out[0] = -v * (1.f / 64.f);
  }
}

extern "C" void kernel_launch(void* const* d_in, const int* in_sizes, int n_in,
                              void* d_out, int out_size, void* d_ws, size_t ws_size,
                              hipStream_t stream) {
  (void)in_sizes; (void)n_in; (void)out_size; (void)ws_size;
  const int*   inp   = (const int*)  d_in[0];
  const int*   tags  = (const int*)  d_in[1];
  const float* emb   = (const float*)d_in[2];
  const float* Wf    = (const float*)d_in[3];
  const float* Uf    = (const float*)d_in[4];
  const float* bfv   = (const float*)d_in[5];
  const float* Wb    = (const float*)d_in[6];
  const float* Ub    = (const float*)d_in[7];
  const float* bbv   = (const float*)d_in[8];
  const float* Wd    = (const float*)d_in[9];
  const float* bd    = (const float*)d_in[10];
  const float* trans = (const float*)d_in[11];
  float* out = (float*)d_out;

  char* ws = (char*)d_ws;
  unsigned* Uq   = (unsigned*)(ws);                 // 512 KB ([dir][u][khalf][g][kk])
  float*    su   = (float*)   (ws + 524288);        // 8 KB
  ushort*   WT16 = (ushort*)  (ws + 1048576);       // 1 MB
  ushort*   Xbf  = (ushort*)  (ws + 2097152);       // 8 MB
  int*      cnt  = (int*)     (ws + 2097152);       // aliases Xbf (dead by k_pot)
  ushort*   Zpf  = (ushort*)  (ws + 10485760);      // 32 MB packed bf16 [tok][j][g]
  ushort*   Zpb  = (ushort*)  (ws + 44040192);      // 32 MB
  ushort*   hf16 = (ushort*)  (ws + 77594624);      // 8 MB
  ushort*   hb16 = (ushort*)  (ws + 85983232);      // 8 MB
  int*      lens = (int*)     (ws + 94371840);      // 256 B
  float*    lln  = (float*)   (ws + 94372096);      // 256 B

  k_prep<<<6160, 256, 0, stream>>>(inp, emb, Wf, Wb, Uf, Ub, WT16, Uq, su, Xbf,
                                   lens, out + 147456);
  k_gemm<<<dim3(128, 8, 2), 256, 0, stream>>>(Xbf, WT16, bfv, bbv, Zpf, Zpb);
  k_recur12<<<128, 512, 0, stream>>>(Zpf, Zpb, Uq, su, lens, hf16, hb16);
  k_pot<<<4096, 256, 0, stream>>>(hf16, hb16, Wd, bd, out, cnt);
  k_post<<<64, 64, 0, stream>>>(out, tags, trans, lens, lln, cnt, out + 147520);
}

// Round 13
// 393.971 us; speedup vs baseline: 1.0450x; 1.0450x over previous
//
#include <hip/hip_runtime.h>

#define B_ 64
#define T_ 256
#define E_ 256
#define H_ 256
#define G4 1024   // 4*H
#define L_ 9

typedef __attribute__((ext_vector_type(8))) short bf16x8;
typedef __attribute__((ext_vector_type(4))) float f32x4;
typedef __attribute__((ext_vector_type(4))) unsigned uint4v;
typedef _Float16 half2v __attribute__((ext_vector_type(2)));

__device__ __forceinline__ ushort f2bf(float x){
  unsigned u = __float_as_uint(x);
  unsigned r = (u + 0x7FFFu + ((u >> 16) & 1u)) >> 16;
  return (ushort)r;
}
__device__ __forceinline__ float bf2f(unsigned u16v){
  return __uint_as_float(u16v << 16);
}
__device__ __forceinline__ float fsig(float x){
  return __builtin_amdgcn_rcpf(1.f + __expf(-x));
}
__device__ __forceinline__ float ftanh(float x){
  return 1.f - 2.f * __builtin_amdgcn_rcpf(__expf(2.f * x) + 1.f);
}
__device__ __forceinline__ int sdot4(unsigned a, unsigned b, int c){
#if __has_builtin(__builtin_amdgcn_sdot4)
  return __builtin_amdgcn_sdot4((int)a, (int)b, c, false);
#else
  int r = c;
  #pragma unroll
  for (int j = 0; j < 4; j++){
    int av = (int)(signed char)((a >> (8 * j)) & 0xFF);
    int bv = (int)(signed char)((b >> (8 * j)) & 0xFF);
    r += av * bv;
  }
  return r;
#endif
}

// ===== fused prep: WT(n'-relay) | Uq(i8, coalesced) | gather | seqlen =====
// WT layout: [dir][n'][k], n' = j*4 + gate  (so Z = X@WT is plain [tok][1024])
__global__ void k_prep(const int* __restrict__ inp, const float* __restrict__ emb,
                       const float* __restrict__ Wf, const float* __restrict__ Wb,
                       const float* __restrict__ Uf, const float* __restrict__ Ub,
                       ushort* __restrict__ WT, unsigned* __restrict__ Uq,
                       float* __restrict__ su, ushort* __restrict__ X,
                       int* __restrict__ lens, float* __restrict__ out_len){
  int bid = blockIdx.x, tid = threadIdx.x;
  if (bid < 2048){                                   // W -> bf16 [dir][n'][k]
    int idx = bid * 256 + tid;
    int dir = idx >> 18; int rem = idx & 262143;
    int np = rem >> 8, k = rem & 255;
    int c = ((np & 3) << 8) | (np >> 2);             // original W column
    const float* W = dir ? Wb : Wf;
    WT[idx] = f2bf(W[k * G4 + c]);
  } else if (bid < 2080){                            // U -> i8 pair-layout, coalesced
    int idx = bid - 2048;                            // 0..31
    int dir = idx >> 4, blk = idx & 15;
    int c0 = blk * 64;                               // column base within dir
    int g = blk >> 2, u0 = (blk & 3) * 64;
    const float* U = dir ? Ub : Uf;
    int cp = tid & 63, ph = tid >> 6;
    __shared__ float redA[4][64];
    __shared__ float rs[64];
    __shared__ unsigned qbuf[64][64];                // [kq][c']
    float am = 0.f;
    for (int kk = 0; kk < 64; ++kk){
      float v = U[(size_t)(kk * 4 + ph) * G4 + c0 + cp];
      am = fmaxf(am, fabsf(v));
    }
    redA[ph][cp] = am;
    __syncthreads();
    if (tid < 64){
      float m = fmaxf(fmaxf(redA[0][tid], redA[1][tid]),
                      fmaxf(redA[2][tid], redA[3][tid]));
      float mm = fmaxf(m, 1e-20f);
      rs[tid] = 127.f / mm;
      su[dir * 1024 + c0 + tid] = mm * (1.f / 127.f);
    }
    __syncthreads();
    float rsv = rs[cp];
    for (int w = 0; w < 16; ++w){
      int kq = ph * 16 + w;
      unsigned word = 0;
      #pragma unroll
      for (int j = 0; j < 4; ++j){
        float v = U[(size_t)(kq * 4 + j) * G4 + c0 + cp];
        int q = __float2int_rn(v * rsv);
        q = max(-127, min(127, q));
        word |= ((unsigned)(q & 0xFF)) << (8 * j);
      }
      qbuf[kq][cp] = word;
    }
    __syncthreads();
    {
      int uu = tid >> 2, part = tid & 3;
      int kh = part >> 1, hs = part & 1;
      unsigned* dst = Uq + dir * 65536 + (u0 + uu) * 256 + kh * 128 + g * 32 + hs * 16;
      #pragma unroll
      for (int w4 = 0; w4 < 4; ++w4){
        int kb = kh * 32 + hs * 16 + w4 * 4;
        uint4 val;
        val.x = qbuf[kb + 0][uu];
        val.y = qbuf[kb + 1][uu];
        val.z = qbuf[kb + 2][uu];
        val.w = qbuf[kb + 3][uu];
        *(uint4*)(dst + w4 * 4) = val;
      }
    }
  } else if (bid < 4128){                            // X = bf16(emb[inp])
    int idx = (bid - 2080) * 256 + tid;
    int m = idx >> 5, koff = (idx & 31) * 8;
    int tok = inp[m];
    const float* src = emb + (size_t)tok * E_ + koff;
    float4 a = *(const float4*)src;
    float4 b = *(const float4*)(src + 4);
    uint4 o;
    o.x = (unsigned)f2bf(a.x) | ((unsigned)f2bf(a.y) << 16);
    o.y = (unsigned)f2bf(a.z) | ((unsigned)f2bf(a.w) << 16);
    o.z = (unsigned)f2bf(b.x) | ((unsigned)f2bf(b.y) << 16);
    o.w = (unsigned)f2bf(b.z) | ((unsigned)f2bf(b.w) << 16);
    *(uint4*)(X + m * E_ + koff) = o;
  } else {                                           // seq_lens: 16 blocks x 4 waves
    int w = tid >> 6, lane = tid & 63;
    int b = (bid - 4128) * 4 + w;
    int c = 0;
    for (int t = lane; t < T_; t += 64) c += (inp[b * T_ + t] != 0);
    for (int off = 32; off; off >>= 1) c += __shfl_xor(c, off);
    if (lane == 0){ lens[b] = c; out_len[b] = (float)c; }
  }
}

// ===== Z = X @ WT + bias (bf16 MFMA) -> bf16 [tok][n'<1024], coalesced stores =====
__global__ __launch_bounds__(256) void k_gemm(const ushort* __restrict__ X,
        const ushort* __restrict__ WT, const float* __restrict__ bf_,
        const float* __restrict__ bb_, ushort* __restrict__ Zpf, ushort* __restrict__ Zpb){
  int zi = blockIdx.z;
  const ushort* wt = WT + zi * 262144;
  const float* bias = zi ? bb_ : bf_;
  ushort* Zp = zi ? Zpb : Zpf;
  int m0 = blockIdx.x * 128, n0 = blockIdx.y * 128;
  __shared__ ushort As[128][40];
  __shared__ ushort Bs[128][40];
  int tid = threadIdx.x;
  int sr = tid >> 1, sk = (tid & 1) * 16;
  const ushort* xg = X + (m0 + sr) * E_ + sk;
  const ushort* wg = wt + (n0 + sr) * E_ + sk;
  f32x4 acc[4][4] = {};
  int lane = tid & 63, wv = tid >> 6;
  int wr = wv >> 1, wc = wv & 1;
  int lrow = lane & 15, kf = (lane >> 4) * 8;
  for (int k0 = 0; k0 < E_; k0 += 32){
    uint4 a0 = *(const uint4*)(xg + k0);
    uint4 a1 = *(const uint4*)(xg + k0 + 8);
    uint4 b0 = *(const uint4*)(wg + k0);
    uint4 b1 = *(const uint4*)(wg + k0 + 8);
    *(uint4*)&As[sr][sk]     = a0;  *(uint4*)&As[sr][sk + 8] = a1;
    *(uint4*)&Bs[sr][sk]     = b0;  *(uint4*)&Bs[sr][sk + 8] = b1;
    __syncthreads();
    bf16x8 af[4], bfr[4];
    #pragma unroll
    for (int i = 0; i < 4; i++) af[i]  = *(const bf16x8*)&As[wr * 64 + i * 16 + lrow][kf];
    #pragma unroll
    for (int i = 0; i < 4; i++) bfr[i] = *(const bf16x8*)&Bs[wc * 64 + i * 16 + lrow][kf];
    #pragma unroll
    for (int i = 0; i < 4; i++)
      #pragma unroll
      for (int j = 0; j < 4; j++)
        acc[i][j] = __builtin_amdgcn_mfma_f32_16x16x32_bf16(af[i], bfr[j], acc[i][j], 0, 0, 0);
    __syncthreads();
  }
  int crow = (lane >> 4) * 4;
  #pragma unroll
  for (int j = 0; j < 4; j++){
    int col = n0 + wc * 64 + j * 16 + lrow;          // n' index
    float bv = bias[((col & 3) << 8) | (col >> 2)];
    #pragma unroll
    for (int i = 0; i < 4; i++){
      int rbase = m0 + wr * 64 + i * 16 + crow;
      #pragma unroll
      for (int r = 0; r < 4; r++)
        Zp[(size_t)(rbase + r) * 1024 + col] = f2bf(acc[i][j][r] + bv);
    }
  }
}

// ===== LSTM recurrence v13: R10 pair layout + HOISTED h ds_reads =====
// 128 WGs x 512 thr. Thread tid: u = tid>>1, khalf = tid&1. One barrier/step.
// All 8 ds_read_b128 of h issued back-to-back before the dot chain (one LDS
// latency per step instead of eight).
__global__ __launch_bounds__(512, 2) void k_recur13(
    const ushort* __restrict__ Zpf, const ushort* __restrict__ Zpb,
    const unsigned* __restrict__ Uq, const float* __restrict__ su,
    const int* __restrict__ lens, ushort* __restrict__ hf16, ushort* __restrict__ hb16){
  int bid = blockIdx.x;
  int dir = bid >> 6, b = bid & 63;
  const uint2* Zp = (const uint2*)(dir ? Zpb : Zpf);
  ushort* H = dir ? hb16 : hf16;
  int tid = threadIdx.x;
  int u = tid >> 1, khalf = tid & 1;
  float sc0 = su[dir * 1024 +        u] * (1.f / 127.f);
  float sc1 = su[dir * 1024 + 256 +  u] * (1.f / 127.f);
  float sc2 = su[dir * 1024 + 512 +  u] * (1.f / 127.f);
  float sc3 = su[dir * 1024 + 768 +  u] * (1.f / 127.f);
  int alen = lens[b];

  // 4 gates x 8 chunks of U (i8) in registers, asm-defined (no rematerialization)
  uint4v uq[4][8];
  {
    const unsigned* p = Uq + dir * 65536 + u * 256 + khalf * 128;
    #pragma unroll
    for (int g = 0; g < 4; g++)
      #pragma unroll
      for (int i = 0; i < 8; i++)
        asm volatile("global_load_dwordx4 %0, %1, off"
                     : "=v"(uq[g][i]) : "v"(p + g * 32 + i * 4));
    asm volatile("s_waitcnt vmcnt(0)" ::: "memory");
    __builtin_amdgcn_sched_barrier(0);
  }

  __shared__ unsigned hq[2][64];     // i8 h, word w = h[4w..4w+3]
  if (tid < 128) ((unsigned*)hq)[tid] = 0u;
  __syncthreads();

  float c_st = 0.f, h_st = 0.f;
  int t0 = dir ? 255 : 0;
  uint2 zw = Zp[(size_t)(b * 256 + t0) * 256 + u];

  for (int s_ = 0; s_ < 256; ++s_){
    int t = dir ? (255 - s_) : s_;
    int tn = dir ? (t - 1) : (t + 1);
    int cur = s_ & 1, nxt = cur ^ 1;
    // prefetch next step's Z (hidden under matvec)
    uint2 zw_n = uint2{0u, 0u};
    if (s_ < 255) zw_n = Zp[(size_t)(b * 256 + tn) * 256 + u];
    // hoist ALL h reads: 8x ds_read_b128 back-to-back, then fence
    const uint4* hp = (const uint4*)&hq[cur][khalf * 32];
    uint4 hv[8];
    #pragma unroll
    for (int i = 0; i < 8; i++) hv[i] = hp[i];
    __builtin_amdgcn_sched_barrier(0);
    // matvec over this thread's k-half, 4 gate accumulators
    int a0 = 0, a1 = 0, a2 = 0, a3 = 0;
    #pragma unroll
    for (int i = 0; i < 8; i++){
      uint4 hvv = hv[i];
      a0 = sdot4(uq[0][i][0], hvv.x, a0);  a0 = sdot4(uq[0][i][1], hvv.y, a0);
      a0 = sdot4(uq[0][i][2], hvv.z, a0);  a0 = sdot4(uq[0][i][3], hvv.w, a0);
      a1 = sdot4(uq[1][i][0], hvv.x, a1);  a1 = sdot4(uq[1][i][1], hvv.y, a1);
      a1 = sdot4(uq[1][i][2], hvv.z, a1);  a1 = sdot4(uq[1][i][3], hvv.w, a1);
      a2 = sdot4(uq[2][i][0], hvv.x, a2);  a2 = sdot4(uq[2][i][1], hvv.y, a2);
      a2 = sdot4(uq[2][i][2], hvv.z, a2);  a2 = sdot4(uq[2][i][3], hvv.w, a2);
      a3 = sdot4(uq[3][i][0], hvv.x, a3);  a3 = sdot4(uq[3][i][1], hvv.y, a3);
      a3 = sdot4(uq[3][i][2], hvv.z, a3);  a3 = sdot4(uq[3][i][3], hvv.w, a3);
    }
    // combine k-halves (pair lanes adjacent)
    a0 += __shfl_xor(a0, 1);
    a1 += __shfl_xor(a1, 1);
    a2 += __shfl_xor(a2, 1);
    a3 += __shfl_xor(a3, 1);
    // activations (redundant on both pair lanes — identical inputs)
    float zi = bf2f(zw.x & 0xffffu) + (float)a0 * sc0;
    float zf = bf2f(zw.x >> 16)     + (float)a1 * sc1;
    float zg = bf2f(zw.y & 0xffffu) + (float)a2 * sc2;
    float zo = bf2f(zw.y >> 16)     + (float)a3 * sc3;
    if (t < alen){
      c_st = fsig(zf) * c_st + fsig(zi) * ftanh(zg);
      h_st = fsig(zo) * ftanh(c_st);
    }
    if (khalf == 0){
      int ri = __float2int_rn(h_st * 127.f);
      ((char*)hq[nxt])[u] = (char)ri;
      H[(size_t)(b * 256 + t) * H_ + u] = f2bf(h_st);
    }
    __syncthreads();
    zw = zw_n;
  }
}

// ===== pot = [hf|hb] @ Wd + bd (one wave per row, bf16 h) =====
__global__ __launch_bounds__(256) void k_pot(const ushort* __restrict__ hf16,
        const ushort* __restrict__ hb16, const float* __restrict__ Wd,
        const float* __restrict__ bd, float* __restrict__ out, int* __restrict__ cnt){
  if (blockIdx.x == 0 && threadIdx.x == 0) *cnt = 0;
  int lane = threadIdx.x & 63, wid = threadIdx.x >> 6;
  int m = blockIdx.x * 4 + wid;
  uint2 ua = *(const uint2*)&hf16[(size_t)m * H_ + lane * 4];
  uint2 ub = *(const uint2*)&hb16[(size_t)m * H_ + lane * 4];
  float av[4] = {bf2f(ua.x & 0xFFFFu), bf2f(ua.x >> 16), bf2f(ua.y & 0xFFFFu), bf2f(ua.y >> 16)};
  float bv[4] = {bf2f(ub.x & 0xFFFFu), bf2f(ub.x >> 16), bf2f(ub.y & 0xFFFFu), bf2f(ub.y >> 16)};
  float acc[9];
  #pragma unroll
  for (int l = 0; l < 9; l++) acc[l] = 0.f;
  #pragma unroll
  for (int i = 0; i < 4; i++){
    int r = lane * 4 + i;
    #pragma unroll
    for (int l = 0; l < 9; l++)
      acc[l] += av[i] * Wd[r * 9 + l] + bv[i] * Wd[(H_ + r) * 9 + l];
  }
  #pragma unroll
  for (int off = 32; off; off >>= 1)
    #pragma unroll
    for (int l = 0; l < 9; l++) acc[l] += __shfl_xor(acc[l], off);
  if (lane == 0){
    #pragma unroll
    for (int l = 0; l < 9; l++) out[(size_t)m * 9 + l] = acc[l] + bd[l];
  }
}

// ===== CRF log-likelihood + loss (fused, last-block reduce) =====
__global__ void k_post(const float* __restrict__ out, const int* __restrict__ tags,
                       const float* __restrict__ trans, const int* __restrict__ lens,
                       float* __restrict__ lln, int* cnt, float* __restrict__ loss_out){
  int b = blockIdx.x, lane = threadIdx.x;
  int len = lens[b];
  const float* pot = out + (size_t)b * T_ * 9;
  float up = 0.f, bp = 0.f;
  for (int t = lane; t < T_; t += 64){
    int tg = tags[b * T_ + t];
    if (t < len) up += pot[t * 9 + tg];
    if (t + 1 < len){
      int tg2 = tags[b * T_ + t + 1];
      bp += trans[tg * 9 + tg2];
    }
  }
  for (int off = 32; off; off >>= 1){ up += __shfl_xor(up, off); bp += __shfl_xor(bp, off); }
  float alpha = 0.f;
  if (lane < 9){
    float tr[9];
    #pragma unroll
    for (int i = 0; i < 9; i++) tr[i] = trans[i * 9 + lane];
    alpha = pot[lane];
    for (int t = 1; t < T_; ++t){
      float v[9];
      #pragma unroll
      for (int i = 0; i < 9; i++) v[i] = __shfl(alpha, i) + tr[i];
      float mx = v[0];
      #pragma unroll
      for (int i = 1; i < 9; i++) mx = fmaxf(mx, v[i]);
      float sum = 0.f;
      #pragma unroll
      for (int i = 0; i < 9; i++) sum += __expf(v[i] - mx);
      float an = pot[t * 9 + lane] + mx + __logf(sum);
      if (t < len) alpha = an;
    }
  }
  float mx2 = -3.4e38f;
  for (int i = 0; i < 9; i++){ float a = __shfl(alpha, i); mx2 = fmaxf(mx2, a); }
  float s2 = 0.f;
  for (int i = 0; i < 9; i++){ float a = __shfl(alpha, i); s2 += __expf(a - mx2); }
  float lse = mx2 + __logf(s2);
  __shared__ int lastf;
  if (lane == 0){
    __hip_atomic_store(&lln[b], (up + bp - lse) / (float)len,
                       __ATOMIC_RELAXED, __HIP_MEMORY_SCOPE_AGENT);
    int old = __hip_atomic_fetch_add(cnt, 1, __ATOMIC_ACQ_REL, __HIP_MEMORY_SCOPE_AGENT);
    lastf = (old == 63);
  }
  __syncthreads();
  if (lastf){
    float v = __hip_atomic_load(&lln[lane], __ATOMIC_RELAXED, __HIP_MEMORY_SCOPE_AGENT);
    for (int off = 32; off; off >>= 1) v += __shfl_xor(v, off);
    if (lane == 0) loss_out[0] = -v * (1.f / 64.f);
  }
}

extern "C" void kernel_launch(void* const* d_in, const int* in_sizes, int n_in,
                              void* d_out, int out_size, void* d_ws, size_t ws_size,
                              hipStream_t stream) {
  (void)in_sizes; (void)n_in; (void)out_size; (void)ws_size;
  const int*   inp   = (const int*)  d_in[0];
  const int*   tags  = (const int*)  d_in[1];
  const float* emb   = (const float*)d_in[2];
  const float* Wf    = (const float*)d_in[3];
  const float* Uf    = (const float*)d_in[4];
  const float* bfv   = (const float*)d_in[5];
  const float* Wb    = (const float*)d_in[6];
  const float* Ub    = (const float*)d_in[7];
  const float* bbv   = (const float*)d_in[8];
  const float* Wd    = (const float*)d_in[9];
  const float* bd    = (const float*)d_in[10];
  const float* trans = (const float*)d_in[11];
  float* out = (float*)d_out;

  char* ws = (char*)d_ws;
  unsigned* Uq   = (unsigned*)(ws);                 // 512 KB ([dir][u][khalf][g][kk])
  float*    su   = (float*)   (ws + 524288);        // 8 KB
  ushort*   WT16 = (ushort*)  (ws + 1048576);       // 1 MB ([dir][n'][k])
  ushort*   Xbf  = (ushort*)  (ws + 2097152);       // 8 MB
  int*      cnt  = (int*)     (ws + 2097152);       // aliases Xbf (dead by k_pot)
  ushort*   Zpf  = (ushort*)  (ws + 10485760);      // 32 MB bf16 [tok][n']
  ushort*   Zpb  = (ushort*)  (ws + 44040192);      // 32 MB
  ushort*   hf16 = (ushort*)  (ws + 77594624);      // 8 MB
  ushort*   hb16 = (ushort*)  (ws + 85983232);      // 8 MB
  int*      lens = (int*)     (ws + 94371840);      // 256 B
  float*    lln  = (float*)   (ws + 94372096);      // 256 B

  k_prep<<<4144, 256, 0, stream>>>(inp, emb, Wf, Wb, Uf, Ub, WT16, Uq, su, Xbf,
                                   lens, out + 147456);
  k_gemm<<<dim3(128, 8, 2), 256, 0, stream>>>(Xbf, WT16, bfv, bbv, Zpf, Zpb);
  k_recur13<<<128, 512, 0, stream>>>(Zpf, Zpb, Uq, su, lens, hf16, hb16);
  k_pot<<<4096, 256, 0, stream>>>(hf16, hb16, Wd, bd, out, cnt);
  k_post<<<64, 64, 0, stream>>>(out, tags, trans, lens, lln, cnt, out + 147520);
}

// Round 14
// 392.670 us; speedup vs baseline: 1.0484x; 1.0033x over previous
//
#include <hip/hip_runtime.h>

#define B_ 64
#define T_ 256
#define E_ 256
#define H_ 256
#define G4 1024   // 4*H
#define L_ 9

typedef __attribute__((ext_vector_type(8))) short bf16x8;
typedef __attribute__((ext_vector_type(4))) float f32x4;
typedef __attribute__((ext_vector_type(4))) unsigned uint4v;
typedef _Float16 half2v __attribute__((ext_vector_type(2)));

__device__ __forceinline__ ushort f2bf(float x){
  unsigned u = __float_as_uint(x);
  unsigned r = (u + 0x7FFFu + ((u >> 16) & 1u)) >> 16;
  return (ushort)r;
}
__device__ __forceinline__ float bf2f(unsigned u16v){
  return __uint_as_float(u16v << 16);
}
__device__ __forceinline__ float fsig(float x){
  return __builtin_amdgcn_rcpf(1.f + __expf(-x));
}
__device__ __forceinline__ float ftanh(float x){
  return 1.f - 2.f * __builtin_amdgcn_rcpf(__expf(2.f * x) + 1.f);
}
__device__ __forceinline__ int sdot4(unsigned a, unsigned b, int c){
#if __has_builtin(__builtin_amdgcn_sdot4)
  return __builtin_amdgcn_sdot4((int)a, (int)b, c, false);
#else
  int r = c;
  #pragma unroll
  for (int j = 0; j < 4; j++){
    int av = (int)(signed char)((a >> (8 * j)) & 0xFF);
    int bv = (int)(signed char)((b >> (8 * j)) & 0xFF);
    r += av * bv;
  }
  return r;
#endif
}

// ===== fused prep: WT(n'-relay) | Uq(i8, coalesced) | gather | seqlen =====
// WT layout: [dir][n'][k], n' = j*4 + gate  (so Z = X@WT is plain [tok][1024])
__global__ void k_prep(const int* __restrict__ inp, const float* __restrict__ emb,
                       const float* __restrict__ Wf, const float* __restrict__ Wb,
                       const float* __restrict__ Uf, const float* __restrict__ Ub,
                       ushort* __restrict__ WT, unsigned* __restrict__ Uq,
                       float* __restrict__ su, ushort* __restrict__ X,
                       int* __restrict__ lens, float* __restrict__ out_len){
  int bid = blockIdx.x, tid = threadIdx.x;
  if (bid < 2048){                                   // W -> bf16 [dir][n'][k]
    int idx = bid * 256 + tid;
    int dir = idx >> 18; int rem = idx & 262143;
    int np = rem >> 8, k = rem & 255;
    int c = ((np & 3) << 8) | (np >> 2);             // original W column
    const float* W = dir ? Wb : Wf;
    WT[idx] = f2bf(W[k * G4 + c]);
  } else if (bid < 2080){                            // U -> i8 pair-layout, coalesced
    int idx = bid - 2048;                            // 0..31
    int dir = idx >> 4, blk = idx & 15;
    int c0 = blk * 64;                               // column base within dir
    int g = blk >> 2, u0 = (blk & 3) * 64;
    const float* U = dir ? Ub : Uf;
    int cp = tid & 63, ph = tid >> 6;
    __shared__ float redA[4][64];
    __shared__ float rs[64];
    __shared__ unsigned qbuf[64][64];                // [kq][c']
    float am = 0.f;
    for (int kk = 0; kk < 64; ++kk){
      float v = U[(size_t)(kk * 4 + ph) * G4 + c0 + cp];
      am = fmaxf(am, fabsf(v));
    }
    redA[ph][cp] = am;
    __syncthreads();
    if (tid < 64){
      float m = fmaxf(fmaxf(redA[0][tid], redA[1][tid]),
                      fmaxf(redA[2][tid], redA[3][tid]));
      float mm = fmaxf(m, 1e-20f);
      rs[tid] = 127.f / mm;
      su[dir * 1024 + c0 + tid] = mm * (1.f / 127.f);
    }
    __syncthreads();
    float rsv = rs[cp];
    for (int w = 0; w < 16; ++w){
      int kq = ph * 16 + w;
      unsigned word = 0;
      #pragma unroll
      for (int j = 0; j < 4; ++j){
        float v = U[(size_t)(kq * 4 + j) * G4 + c0 + cp];
        int q = __float2int_rn(v * rsv);
        q = max(-127, min(127, q));
        word |= ((unsigned)(q & 0xFF)) << (8 * j);
      }
      qbuf[kq][cp] = word;
    }
    __syncthreads();
    {
      int uu = tid >> 2, part = tid & 3;
      int kh = part >> 1, hs = part & 1;
      unsigned* dst = Uq + dir * 65536 + (u0 + uu) * 256 + kh * 128 + g * 32 + hs * 16;
      #pragma unroll
      for (int w4 = 0; w4 < 4; ++w4){
        int kb = kh * 32 + hs * 16 + w4 * 4;
        uint4 val;
        val.x = qbuf[kb + 0][uu];
        val.y = qbuf[kb + 1][uu];
        val.z = qbuf[kb + 2][uu];
        val.w = qbuf[kb + 3][uu];
        *(uint4*)(dst + w4 * 4) = val;
      }
    }
  } else if (bid < 4128){                            // X = bf16(emb[inp])
    int idx = (bid - 2080) * 256 + tid;
    int m = idx >> 5, koff = (idx & 31) * 8;
    int tok = inp[m];
    const float* src = emb + (size_t)tok * E_ + koff;
    float4 a = *(const float4*)src;
    float4 b = *(const float4*)(src + 4);
    uint4 o;
    o.x = (unsigned)f2bf(a.x) | ((unsigned)f2bf(a.y) << 16);
    o.y = (unsigned)f2bf(a.z) | ((unsigned)f2bf(a.w) << 16);
    o.z = (unsigned)f2bf(b.x) | ((unsigned)f2bf(b.y) << 16);
    o.w = (unsigned)f2bf(b.z) | ((unsigned)f2bf(b.w) << 16);
    *(uint4*)(X + m * E_ + koff) = o;
  } else {                                           // seq_lens: 16 blocks x 4 waves
    int w = tid >> 6, lane = tid & 63;
    int b = (bid - 4128) * 4 + w;
    int c = 0;
    for (int t = lane; t < T_; t += 64) c += (inp[b * T_ + t] != 0);
    for (int off = 32; off; off >>= 1) c += __shfl_xor(c, off);
    if (lane == 0){ lens[b] = c; out_len[b] = (float)c; }
  }
}

// ===== Z = X @ WT + bias (bf16 MFMA, m97 structure: global_load_lds width=16) =====
// -> bf16 [tok][n'<1024], coalesced stores. 128x128 tile, BK=32, linear LDS.
__global__ __launch_bounds__(256) void k_gemm(const ushort* __restrict__ X,
        const ushort* __restrict__ WT, const float* __restrict__ bf_,
        const float* __restrict__ bb_, ushort* __restrict__ Zpf, ushort* __restrict__ Zpb){
  int zi = blockIdx.z;
  const ushort* wt = WT + zi * 262144;
  const float* bias = zi ? bb_ : bf_;
  ushort* Zp = zi ? Zpb : Zpf;
  int m0 = blockIdx.x * 128, n0 = blockIdx.y * 128;
  __shared__ ushort As[128 * 32];
  __shared__ ushort Bs[128 * 32];
  int tid = threadIdx.x;
  int lane = tid & 63, w = tid >> 6;
  int wr = w >> 1, wc = w & 1;
  int srow = lane >> 2, skq = lane & 3;              // staging: lane -> (row, 16B col)
  int lr = lane & 15, kf8 = (lane >> 4) * 8;         // frag indices
  f32x4 acc[4][4] = {};
  for (int k0 = 0; k0 < E_; k0 += 32){
    #pragma unroll
    for (int j = 0; j < 2; j++){
      int rg = (w * 2 + j) * 16;                     // 16-row group this wave loads
      const ushort* ga = X  + (size_t)(m0 + rg + srow) * E_ + k0 + skq * 8;
      const ushort* gb = wt + (size_t)(n0 + rg + srow) * E_ + k0 + skq * 8;
      __builtin_amdgcn_global_load_lds(
          (const __attribute__((address_space(1))) unsigned*)ga,
          (__attribute__((address_space(3))) unsigned*)&As[rg * 32], 16, 0, 0);
      __builtin_amdgcn_global_load_lds(
          (const __attribute__((address_space(1))) unsigned*)gb,
          (__attribute__((address_space(3))) unsigned*)&Bs[rg * 32], 16, 0, 0);
    }
    __syncthreads();
    bf16x8 af[4], bfr[4];
    #pragma unroll
    for (int i = 0; i < 4; i++){
      af[i]  = *(const bf16x8*)&As[(wr * 64 + i * 16 + lr) * 32 + kf8];
      bfr[i] = *(const bf16x8*)&Bs[(wc * 64 + i * 16 + lr) * 32 + kf8];
    }
    #pragma unroll
    for (int i = 0; i < 4; i++)
      #pragma unroll
      for (int j = 0; j < 4; j++)
        acc[i][j] = __builtin_amdgcn_mfma_f32_16x16x32_bf16(af[i], bfr[j], acc[i][j], 0, 0, 0);
    __syncthreads();
  }
  int crow = (lane >> 4) * 4;
  #pragma unroll
  for (int j = 0; j < 4; j++){
    int col = n0 + wc * 64 + j * 16 + lr;            // n' index
    float bv = bias[((col & 3) << 8) | (col >> 2)];
    #pragma unroll
    for (int i = 0; i < 4; i++){
      int rbase = m0 + wr * 64 + i * 16 + crow;
      #pragma unroll
      for (int r = 0; r < 4; r++)
        Zp[(size_t)(rbase + r) * 1024 + col] = f2bf(acc[i][j][r] + bv);
    }
  }
}

// ===== LSTM recurrence v13: pair layout + hoisted h ds_reads (unchanged) =====
__global__ __launch_bounds__(512, 2) void k_recur13(
    const ushort* __restrict__ Zpf, const ushort* __restrict__ Zpb,
    const unsigned* __restrict__ Uq, const float* __restrict__ su,
    const int* __restrict__ lens, ushort* __restrict__ hf16, ushort* __restrict__ hb16){
  int bid = blockIdx.x;
  int dir = bid >> 6, b = bid & 63;
  const uint2* Zp = (const uint2*)(dir ? Zpb : Zpf);
  ushort* H = dir ? hb16 : hf16;
  int tid = threadIdx.x;
  int u = tid >> 1, khalf = tid & 1;
  float sc0 = su[dir * 1024 +        u] * (1.f / 127.f);
  float sc1 = su[dir * 1024 + 256 +  u] * (1.f / 127.f);
  float sc2 = su[dir * 1024 + 512 +  u] * (1.f / 127.f);
  float sc3 = su[dir * 1024 + 768 +  u] * (1.f / 127.f);
  int alen = lens[b];

  uint4v uq[4][8];
  {
    const unsigned* p = Uq + dir * 65536 + u * 256 + khalf * 128;
    #pragma unroll
    for (int g = 0; g < 4; g++)
      #pragma unroll
      for (int i = 0; i < 8; i++)
        asm volatile("global_load_dwordx4 %0, %1, off"
                     : "=v"(uq[g][i]) : "v"(p + g * 32 + i * 4));
    asm volatile("s_waitcnt vmcnt(0)" ::: "memory");
    __builtin_amdgcn_sched_barrier(0);
  }

  __shared__ unsigned hq[2][64];     // i8 h, word w = h[4w..4w+3]
  if (tid < 128) ((unsigned*)hq)[tid] = 0u;
  __syncthreads();

  float c_st = 0.f, h_st = 0.f;
  int t0 = dir ? 255 : 0;
  uint2 zw = Zp[(size_t)(b * 256 + t0) * 256 + u];

  for (int s_ = 0; s_ < 256; ++s_){
    int t = dir ? (255 - s_) : s_;
    int tn = dir ? (t - 1) : (t + 1);
    int cur = s_ & 1, nxt = cur ^ 1;
    uint2 zw_n = uint2{0u, 0u};
    if (s_ < 255) zw_n = Zp[(size_t)(b * 256 + tn) * 256 + u];
    const uint4* hp = (const uint4*)&hq[cur][khalf * 32];
    uint4 hv[8];
    #pragma unroll
    for (int i = 0; i < 8; i++) hv[i] = hp[i];
    __builtin_amdgcn_sched_barrier(0);
    int a0 = 0, a1 = 0, a2 = 0, a3 = 0;
    #pragma unroll
    for (int i = 0; i < 8; i++){
      uint4 hvv = hv[i];
      a0 = sdot4(uq[0][i][0], hvv.x, a0);  a0 = sdot4(uq[0][i][1], hvv.y, a0);
      a0 = sdot4(uq[0][i][2], hvv.z, a0);  a0 = sdot4(uq[0][i][3], hvv.w, a0);
      a1 = sdot4(uq[1][i][0], hvv.x, a1);  a1 = sdot4(uq[1][i][1], hvv.y, a1);
      a1 = sdot4(uq[1][i][2], hvv.z, a1);  a1 = sdot4(uq[1][i][3], hvv.w, a1);
      a2 = sdot4(uq[2][i][0], hvv.x, a2);  a2 = sdot4(uq[2][i][1], hvv.y, a2);
      a2 = sdot4(uq[2][i][2], hvv.z, a2);  a2 = sdot4(uq[2][i][3], hvv.w, a2);
      a3 = sdot4(uq[3][i][0], hvv.x, a3);  a3 = sdot4(uq[3][i][1], hvv.y, a3);
      a3 = sdot4(uq[3][i][2], hvv.z, a3);  a3 = sdot4(uq[3][i][3], hvv.w, a3);
    }
    a0 += __shfl_xor(a0, 1);
    a1 += __shfl_xor(a1, 1);
    a2 += __shfl_xor(a2, 1);
    a3 += __shfl_xor(a3, 1);
    float zi = bf2f(zw.x & 0xffffu) + (float)a0 * sc0;
    float zf = bf2f(zw.x >> 16)     + (float)a1 * sc1;
    float zg = bf2f(zw.y & 0xffffu) + (float)a2 * sc2;
    float zo = bf2f(zw.y >> 16)     + (float)a3 * sc3;
    if (t < alen){
      c_st = fsig(zf) * c_st + fsig(zi) * ftanh(zg);
      h_st = fsig(zo) * ftanh(c_st);
    }
    if (khalf == 0){
      int ri = __float2int_rn(h_st * 127.f);
      ((char*)hq[nxt])[u] = (char)ri;
      H[(size_t)(b * 256 + t) * H_ + u] = f2bf(h_st);
    }
    __syncthreads();
    zw = zw_n;
  }
}

// ===== pot = [hf|hb] @ Wd + bd (one wave per row, bf16 h) =====
__global__ __launch_bounds__(256) void k_pot(const ushort* __restrict__ hf16,
        const ushort* __restrict__ hb16, const float* __restrict__ Wd,
        const float* __restrict__ bd, float* __restrict__ out, int* __restrict__ cnt){
  if (blockIdx.x == 0 && threadIdx.x == 0) *cnt = 0;
  int lane = threadIdx.x & 63, wid = threadIdx.x >> 6;
  int m = blockIdx.x * 4 + wid;
  uint2 ua = *(const uint2*)&hf16[(size_t)m * H_ + lane * 4];
  uint2 ub = *(const uint2*)&hb16[(size_t)m * H_ + lane * 4];
  float av[4] = {bf2f(ua.x & 0xFFFFu), bf2f(ua.x >> 16), bf2f(ua.y & 0xFFFFu), bf2f(ua.y >> 16)};
  float bv[4] = {bf2f(ub.x & 0xFFFFu), bf2f(ub.x >> 16), bf2f(ub.y & 0xFFFFu), bf2f(ub.y >> 16)};
  float acc[9];
  #pragma unroll
  for (int l = 0; l < 9; l++) acc[l] = 0.f;
  #pragma unroll
  for (int i = 0; i < 4; i++){
    int r = lane * 4 + i;
    #pragma unroll
    for (int l = 0; l < 9; l++)
      acc[l] += av[i] * Wd[r * 9 + l] + bv[i] * Wd[(H_ + r) * 9 + l];
  }
  #pragma unroll
  for (int off = 32; off; off >>= 1)
    #pragma unroll
    for (int l = 0; l < 9; l++) acc[l] += __shfl_xor(acc[l], off);
  if (lane == 0){
    #pragma unroll
    for (int l = 0; l < 9; l++) out[(size_t)m * 9 + l] = acc[l] + bd[l];
  }
}

// ===== CRF log-likelihood + loss (fused, last-block reduce) =====
__global__ void k_post(const float* __restrict__ out, const int* __restrict__ tags,
                       const float* __restrict__ trans, const int* __restrict__ lens,
                       float* __restrict__ lln, int* cnt, float* __restrict__ loss_out){
  int b = blockIdx.x, lane = threadIdx.x;
  int len = lens[b];
  const float* pot = out + (size_t)b * T_ * 9;
  float up = 0.f, bp = 0.f;
  for (int t = lane; t < T_; t += 64){
    int tg = tags[b * T_ + t];
    if (t < len) up += pot[t * 9 + tg];
    if (t + 1 < len){
      int tg2 = tags[b * T_ + t + 1];
      bp += trans[tg * 9 + tg2];
    }
  }
  for (int off = 32; off; off >>= 1){ up += __shfl_xor(up, off); bp += __shfl_xor(bp, off); }
  float alpha = 0.f;
  if (lane < 9){
    float tr[9];
    #pragma unroll
    for (int i = 0; i < 9; i++) tr[i] = trans[i * 9 + lane];
    alpha = pot[lane];
    for (int t = 1; t < T_; ++t){
      float v[9];
      #pragma unroll
      for (int i = 0; i < 9; i++) v[i] = __shfl(alpha, i) + tr[i];
      float mx = v[0];
      #pragma unroll
      for (int i = 1; i < 9; i++) mx = fmaxf(mx, v[i]);
      float sum = 0.f;
      #pragma unroll
      for (int i = 0; i < 9; i++) sum += __expf(v[i] - mx);
      float an = pot[t * 9 + lane] + mx + __logf(sum);
      if (t < len) alpha = an;
    }
  }
  float mx2 = -3.4e38f;
  for (int i = 0; i < 9; i++){ float a = __shfl(alpha, i); mx2 = fmaxf(mx2, a); }
  float s2 = 0.f;
  for (int i = 0; i < 9; i++){ float a = __shfl(alpha, i); s2 += __expf(a - mx2); }
  float lse = mx2 + __logf(s2);
  __shared__ int lastf;
  if (lane == 0){
    __hip_atomic_store(&lln[b], (up + bp - lse) / (float)len,
                       __ATOMIC_RELAXED, __HIP_MEMORY_SCOPE_AGENT);
    int old = __hip_atomic_fetch_add(cnt, 1, __ATOMIC_ACQ_REL, __HIP_MEMORY_SCOPE_AGENT);
    lastf = (old == 63);
  }
  __syncthreads();
  if (lastf){
    float v = __hip_atomic_load(&lln[lane], __ATOMIC_RELAXED, __HIP_MEMORY_SCOPE_AGENT);
    for (int off = 32; off; off >>= 1) v += __shfl_xor(v, off);
    if (lane == 0) loss_out[0] = -v * (1.f / 64.f);
  }
}

extern "C" void kernel_launch(void* const* d_in, const int* in_sizes, int n_in,
                              void* d_out, int out_size, void* d_ws, size_t ws_size,
                              hipStream_t stream) {
  (void)in_sizes; (void)n_in; (void)out_size; (void)ws_size;
  const int*   inp   = (const int*)  d_in[0];
  const int*   tags  = (const int*)  d_in[1];
  const float* emb   = (const float*)d_in[2];
  const float* Wf    = (const float*)d_in[3];
  const float* Uf    = (const float*)d_in[4];
  const float* bfv   = (const float*)d_in[5];
  const float* Wb    = (const float*)d_in[6];
  const float* Ub    = (const float*)d_in[7];
  const float* bbv   = (const float*)d_in[8];
  const float* Wd    = (const float*)d_in[9];
  const float* bd    = (const float*)d_in[10];
  const float* trans = (const float*)d_in[11];
  float* out = (float*)d_out;

  char* ws = (char*)d_ws;
  unsigned* Uq   = (unsigned*)(ws);                 // 512 KB ([dir][u][khalf][g][kk])
  float*    su   = (float*)   (ws + 524288);        // 8 KB
  ushort*   WT16 = (ushort*)  (ws + 1048576);       // 1 MB ([dir][n'][k])
  ushort*   Xbf  = (ushort*)  (ws + 2097152);       // 8 MB
  int*      cnt  = (int*)     (ws + 2097152);       // aliases Xbf (dead by k_pot)
  ushort*   Zpf  = (ushort*)  (ws + 10485760);      // 32 MB bf16 [tok][n']
  ushort*   Zpb  = (ushort*)  (ws + 44040192);      // 32 MB
  ushort*   hf16 = (ushort*)  (ws + 77594624);      // 8 MB
  ushort*   hb16 = (ushort*)  (ws + 85983232);      // 8 MB
  int*      lens = (int*)     (ws + 94371840);      // 256 B
  float*    lln  = (float*)   (ws + 94372096);      // 256 B

  k_prep<<<4144, 256, 0, stream>>>(inp, emb, Wf, Wb, Uf, Ub, WT16, Uq, su, Xbf,
                                   lens, out + 147456);
  k_gemm<<<dim3(128, 8, 2), 256, 0, stream>>>(Xbf, WT16, bfv, bbv, Zpf, Zpb);
  k_recur13<<<128, 512, 0, stream>>>(Zpf, Zpb, Uq, su, lens, hf16, hb16);
  k_pot<<<4096, 256, 0, stream>>>(hf16, hb16, Wd, bd, out, cnt);
  k_post<<<64, 64, 0, stream>>>(out, tags, trans, lens, lln, cnt, out + 147520);
}